// Round 23
// baseline (134.139 us; speedup 1.0000x reference)
//
#include <hip/hip_runtime.h>

typedef unsigned short u16;
typedef unsigned int u32;
typedef unsigned long long u64;

using bf16x8 = __bf16 __attribute__((ext_vector_type(8)));
using f32x4  = float  __attribute__((ext_vector_type(4)));

#define LDS_SPACE __attribute__((address_space(3)))
#define GLB_SPACE __attribute__((address_space(1)))

static __device__ __forceinline__ u16 f2bf(float f) {
  union { float f; u32 u; } c; c.f = f;
  u32 u = c.u;
  return (u16)((u + 0x7fffu + ((u >> 16) & 1u)) >> 16);   // RNE
}
static __device__ __forceinline__ float bf2f(u16 u) {
  union { u32 u; float f; } c; c.u = ((u32)u) << 16;
  return c.f;
}
static __device__ __forceinline__ float fmax3(float a, float b, float c) {
  return fmaxf(fmaxf(a, b), c);               // clang fuses to v_max3_f32
}

static __device__ __forceinline__ void fence_barrier() {
  asm volatile("" ::: "memory");
  __builtin_amdgcn_s_barrier();
  asm volatile("" ::: "memory");
}

constexpr float SC = 0.18033688011112042f;    // log2(e)/8 (folded into wq)

// items per head, sorted by descending chunk length (qt*4 + ch)
__device__ __constant__ unsigned char kItems[40] = {
  // len 8
  12, 28, 29, 42, 44, 45, 46, 57, 59, 60, 61, 62, 63,
  // len 7
  24, 25, 37, 38, 40, 41, 49, 51, 52, 53, 54, 55, 56, 58,
  // len 6
  8, 20, 21, 32, 33, 34, 36, 48, 50,
  // len 5
  16, 17,
  // len 4
  4,
  // len 2
  0
};

// ---------------- fused prep: x->bf16 convert + 4 weight transposes ----------
__global__ __launch_bounds__(256) void prep_k(const float* __restrict__ x,
                                              const float* __restrict__ wq,
                                              const float* __restrict__ wk,
                                              const float* __restrict__ wv,
                                              const float* __restrict__ wo,
                                              u16* __restrict__ x_bf,
                                              u16* __restrict__ wqkv_t,
                                              u16* __restrict__ wo_t) {
  const int b = blockIdx.x;
  if (b < 4096) {
    int i = b * 256 + threadIdx.x;
    float4 v = ((const float4*)x)[i];
    ushort4 o;
    o.x = f2bf(v.x); o.y = f2bf(v.y); o.z = f2bf(v.z); o.w = f2bf(v.w);
    ((ushort4*)x_bf)[i] = o;
    return;
  }
  const float* src; u16* dst; int C, bx, by; float scale = 1.0f;
  if (b < 8192)      { src = wq; dst = wqkv_t; C = 2048; int t = b - 4096; bx = t & 63; by = t >> 6; scale = SC; }
  else if (b < 9216) { src = wk; dst = wqkv_t + (size_t)2048 * 2048; C = 512; int t = b - 8192; bx = t & 15; by = t >> 4; }
  else if (b < 10240){ src = wv; dst = wqkv_t + (size_t)2560 * 2048; C = 512; int t = b - 9216; bx = t & 15; by = t >> 4; }
  else               { src = wo; dst = wo_t; C = 2048; int t = b - 10240; bx = t & 63; by = t >> 6; }
  __shared__ float t[32][33];
  const int lx = threadIdx.x & 31, ly = threadIdx.x >> 5;
  const int r0 = by * 32, c0 = bx * 32;
  #pragma unroll
  for (int i = 0; i < 32; i += 8)
    t[ly + i][lx] = src[(size_t)(r0 + ly + i) * C + c0 + lx];
  __syncthreads();
  #pragma unroll
  for (int i = 0; i < 32; i += 8)
    dst[(size_t)(c0 + ly + i) * 2048 + r0 + lx] = f2bf(t[lx][ly + i] * scale);
}

// ---------------- merged RoPE (Q|K cols) + V transpose (disjoint cols) -------
__global__ __launch_bounds__(256) void ropevt_k(u16* __restrict__ Y,
                                                const float* __restrict__ freq,
                                                u16* __restrict__ Vt) {
  const int b = blockIdx.x;
  if (b < 10240) {
    int idx = b * 256 + threadIdx.x;
    int s = idx / 1280;
    int rem = idx - s * 1280;
    int h = rem >> 5;
    int i = rem & 31;
    int col = (h < 32) ? (h * 64 + 2 * i) : (2048 + (h - 32) * 64 + 2 * i);
    float ang = freq[s * 32 + i];
    float sn, cs;
    sincosf(ang, &sn, &cs);
    size_t base = (size_t)s * 3072 + col;
    float e = bf2f(Y[base]), o = bf2f(Y[base + 1]);
    Y[base]     = f2bf(e * cs - o * sn);
    Y[base + 1] = f2bf(e * sn + o * cs);
    return;
  }
  __shared__ u16 t[64][72];
  const int tb = b - 10240;                  // 0..255
  const int s0 = (tb & 31) * 64;
  const int c0 = (tb >> 5) * 64;
  const int lx = threadIdx.x & 63, ly = threadIdx.x >> 6;
  #pragma unroll
  for (int i = 0; i < 64; i += 4)
    t[i + ly][lx] = Y[(size_t)(s0 + i + ly) * 3072 + 2560 + c0 + lx];
  __syncthreads();
  #pragma unroll
  for (int i = 0; i < 64; i += 4)
    Vt[(size_t)(c0 + i + ly) * 2048 + s0 + lx] = t[lx][i + ly];
}

// ------- GEMM: C[M][N]=A[M][K]*Bt[N][K]^T, BM=64, BN templated, BK=64 -------
// 1D grid + bijective XCD swizzle (nwg % 8 == 0): chunk per XCD -> L2 locality.
template <typename OutT, int BN, int GX>
__global__ __launch_bounds__(256) void gemm64_k(const u16* __restrict__ A,
                                                const u16* __restrict__ Bt,
                                                OutT* __restrict__ C,
                                                int M, int N, int K) {
  constexpr int WN = BN / 32;
  __shared__ u16 As[2][64 * 64];
  __shared__ u16 Bs[2][BN * 64];
  const int tid = threadIdx.x, lane = tid & 63, w = tid >> 6;
  const int wr = w >> 1, wc = w & 1;
  const int nwg = gridDim.x;
  const int bsw = (blockIdx.x & 7) * (nwg >> 3) + ((int)blockIdx.x >> 3);
  const int bm = bsw / GX, bn = bsw - bm * GX;
  const int l15 = lane & 15, lq = lane >> 4;
  f32x4 acc[2][WN] = {};

  const int srow8 = lane >> 3;
  const int scolb = ((lane & 7) ^ srow8) * 16;
  const u16* AgR = A + (size_t)(bm * 64 + w * 16 + srow8) * K;
  const u16* BgR = Bt + (size_t)(bn * BN + w * (BN / 4) + srow8) * K;

  auto stage = [&](int buf, int k0) {
    #pragma unroll
    for (int i = 0; i < 2; ++i)
      __builtin_amdgcn_global_load_lds(
          (const GLB_SPACE u32*)((const char*)(AgR + (size_t)i * 8 * K + k0) + scolb),
          (LDS_SPACE u32*)&As[buf][(w * 16 + i * 8) * 64], 16, 0, 0);
    #pragma unroll
    for (int i = 0; i < WN; ++i)
      __builtin_amdgcn_global_load_lds(
          (const GLB_SPACE u32*)((const char*)(BgR + (size_t)i * 8 * K + k0) + scolb),
          (LDS_SPACE u32*)&Bs[buf][(w * (BN / 4) + i * 8) * 64], 16, 0, 0);
  };

  stage(0, 0);
  asm volatile("s_waitcnt vmcnt(0)" ::: "memory");
  fence_barrier();

  for (int k0 = 0; k0 < K; k0 += 64) {
    const int p = (k0 >> 6) & 1;
    if (k0 + 64 < K) stage(p ^ 1, k0 + 64);

    #pragma unroll
    for (int kk = 0; kk < 2; ++kk) {
      bf16x8 a[2], b[WN];
      #pragma unroll
      for (int m = 0; m < 2; ++m) {
        const int ra = wr * 32 + m * 16 + l15;
        a[m] = *(const bf16x8*)&As[p][ra * 64 + (((kk * 4 + lq) ^ (ra & 7)) << 3)];
      }
      #pragma unroll
      for (int n = 0; n < WN; ++n) {
        const int rb = wc * (BN / 2) + n * 16 + l15;
        b[n] = *(const bf16x8*)&Bs[p][rb * 64 + (((kk * 4 + lq) ^ (rb & 7)) << 3)];
      }
      #pragma unroll
      for (int m = 0; m < 2; ++m)
        #pragma unroll
        for (int n = 0; n < WN; ++n)
          acc[m][n] = __builtin_amdgcn_mfma_f32_16x16x32_bf16(a[m], b[n], acc[m][n], 0, 0, 0);
    }

    asm volatile("s_waitcnt vmcnt(0)" ::: "memory");
    fence_barrier();
  }

  const int r0 = bm * 64 + wr * 32 + lq * 4;
  const int c0 = bn * BN + wc * (BN / 2) + l15;
  #pragma unroll
  for (int m = 0; m < 2; ++m)
    #pragma unroll
    for (int n = 0; n < WN; ++n)
      #pragma unroll
      for (int r = 0; r < 4; ++r) {
        float v = acc[m][n][r];
        size_t off = (size_t)(r0 + m * 16 + r) * N + (c0 + n * 16);
        if constexpr (sizeof(OutT) == 2) ((u16*)C)[off] = f2bf(v);
        else C[off] = v;
      }
}

// ---------------- Split-K flash attention: single-buffer K/V -----------------
// l via ones-A MFMA; max via v_max3. Stable best config (~51us).
__global__ __launch_bounds__(256, 3) void attn_part_k(const u16* __restrict__ Y,
                                                      const u16* __restrict__ Vtg,
                                                      u16* __restrict__ Opart,
                                                      float2* __restrict__ Ml,
                                                      u16* __restrict__ Out) {
  __shared__ u16 Ks[64 * 64];
  __shared__ u16 Vs[64 * 64];
  __shared__ u32 Ps[4][16 * 32];
  const int w = threadIdx.x >> 6, lane = threadIdx.x & 63;
  const int l15 = lane & 15, lq = lane >> 4;

  const int b = (int)blockIdx.x;
  const int head = b & 31;
  const int idx = b >> 5;                      // 0..39, descending chunk length
  const int v = kItems[idx];
  const int qt = v >> 2, ch = v & 3;
  const int kvh = head >> 2;
  const int ntiles = 2 * qt + 2;
  const int nch = qt < 4 ? 1 : qt < 8 ? 2 : qt < 12 ? 3 : 4;
  const int tstart = (ch * ntiles) / nch;
  const int tend = ((ch + 1) * ntiles) / nch;
  const int q0w = qt * 128 + w * 32;

  const int srow = lane >> 3;
  const int scolb = ((lane & 7) ^ srow) * 16;
  const char* gkB = (const char*)(Y + (size_t)(w * 16 + srow) * 3072 + 2048 + kvh * 64) + scolb;
  const char* gvB = (const char*)(Vtg + (size_t)(kvh * 64 + w * 16 + srow) * 2048) + scolb;

  auto stage = [&](int t) {
    const size_t t0 = (size_t)t * 64;
    #pragma unroll
    for (int i = 0; i < 2; ++i) {
      __builtin_amdgcn_global_load_lds((const GLB_SPACE u32*)(gkB + t0 * 6144 + (size_t)i * 49152),
                                       (LDS_SPACE u32*)&Ks[(w * 16 + i * 8) * 64], 16, 0, 0);
      __builtin_amdgcn_global_load_lds((const GLB_SPACE u32*)(gvB + t0 * 2 + (size_t)i * 32768),
                                       (LDS_SPACE u32*)&Vs[(w * 16 + i * 8) * 64], 16, 0, 0);
    }
  };

  // hoisted LDS byte offsets
  int rowB[4], xk[2], pwr[4], prd[2];
  #pragma unroll
  for (int kt = 0; kt < 4; ++kt) rowB[kt] = (kt * 16 + l15) * 128;
  #pragma unroll
  for (int kk = 0; kk < 2; ++kk) xk[kk] = (((kk * 4 + lq) ^ (l15 & 7)) << 4);
  #pragma unroll
  for (int n = 0; n < 4; ++n)
    pwr[n] = (l15 * 32 + ((lq * 2 + n * 8) ^ ((l15 & 7) << 2))) * 4;
  #pragma unroll
  for (int c = 0; c < 2; ++c)
    prd[c] = l15 * 128 + (((c * 32 + lq * 8) ^ ((l15 & 7) << 3)) << 1);

  bf16x8 ones;
  {
    union { u16 u; __bf16 h; } cv; cv.u = 0x3F80;   // bf16 1.0
    #pragma unroll
    for (int i = 0; i < 8; ++i) ones[i] = cv.h;
  }

  bf16x8 qf[2][2];
  #pragma unroll
  for (int qs = 0; qs < 2; ++qs)
    #pragma unroll
    for (int kk = 0; kk < 2; ++kk)
      qf[qs][kk] = *(const bf16x8*)&Y[(size_t)(q0w + qs * 16 + l15) * 3072 +
                                      head * 64 + kk * 32 + lq * 8];

  float m_[2] = { -1e30f, -1e30f };
  f32x4 accL[2] = {};                          // row sums via ones-MFMA
  f32x4 accO[2][4] = {};

  for (int t = tstart; t < tend; ++t) {
    stage(t);
    asm volatile("s_waitcnt vmcnt(0)" ::: "memory");
    fence_barrier();                          // buffer ready

    const int t0 = t * 64;
    if (t0 <= q0w + 31) {
      const char* KbC = (const char*)Ks;
      const char* VbC = (const char*)Vs;

      f32x4 sc[2][4] = {};
      #pragma unroll
      for (int kk = 0; kk < 2; ++kk)
        #pragma unroll
        for (int kt = 0; kt < 4; ++kt) {
          bf16x8 a = *(const bf16x8*)(KbC + rowB[kt] + xk[kk]);
          sc[0][kt] = __builtin_amdgcn_mfma_f32_16x16x32_bf16(a, qf[0][kk], sc[0][kt], 0, 0, 0);
          sc[1][kt] = __builtin_amdgcn_mfma_f32_16x16x32_bf16(a, qf[1][kk], sc[1][kt], 0, 0, 0);
        }

      bf16x8 vf[2][4];
      #pragma unroll
      for (int c = 0; c < 2; ++c)
        #pragma unroll
        for (int dt = 0; dt < 4; ++dt)
          vf[c][dt] = *(const bf16x8*)(VbC + rowB[dt] + xk[c]);

      #pragma unroll
      for (int qs = 0; qs < 2; ++qs) {
        const int qsmin = q0w + qs * 16;
        if (t0 > qsmin + 15) continue;
        const int qrow = qsmin + l15;
        if (t0 + 63 > qsmin) {
          #pragma unroll
          for (int n = 0; n < 4; ++n)
            #pragma unroll
            for (int rr = 0; rr < 4; ++rr)
              if (t0 + n * 16 + lq * 4 + rr > qrow) sc[qs][n][rr] = -1e30f;
        }
        // v_max3 tree (8 ops over 16 values)
        float mx = fmaxf(
            fmax3(fmax3(sc[qs][0][0], sc[qs][0][1], sc[qs][0][2]),
                  fmax3(sc[qs][0][3], sc[qs][1][0], sc[qs][1][1]),
                  fmax3(sc[qs][1][2], sc[qs][1][3], sc[qs][2][0])),
            fmax3(fmax3(sc[qs][2][1], sc[qs][2][2], sc[qs][2][3]),
                  fmax3(sc[qs][3][0], sc[qs][3][1], sc[qs][3][2]),
                  sc[qs][3][3]));

        if (__any(mx > m_[qs] + 7.25f)) {      // rare rescale (defer-max)
          float mf = mx;
          mf = fmaxf(mf, __shfl_xor(mf, 16));
          mf = fmaxf(mf, __shfl_xor(mf, 32));
          const float mnew = fmaxf(m_[qs], mf);
          const float alpha = exp2f(m_[qs] - mnew);
          accL[qs] *= alpha;
          #pragma unroll
          for (int dt = 0; dt < 4; ++dt) accO[qs][dt] *= alpha;
          m_[qs] = mnew;
        }
        const float mS = m_[qs];
        char* psB = (char*)Ps[w];
        #pragma unroll
        for (int n = 0; n < 4; ++n) {
          float p0 = exp2f(sc[qs][n][0] - mS);
          float p1 = exp2f(sc[qs][n][1] - mS);
          float p2 = exp2f(sc[qs][n][2] - mS);
          float p3 = exp2f(sc[qs][n][3] - mS);
          u32 w0, w1;
          asm("v_cvt_pk_bf16_f32 %0, %1, %2" : "=v"(w0) : "v"(p0), "v"(p1));
          asm("v_cvt_pk_bf16_f32 %0, %1, %2" : "=v"(w1) : "v"(p2), "v"(p3));
          *(u64*)(psB + pwr[n]) = (u64)w0 | ((u64)w1 << 32);
        }

        #pragma unroll
        for (int c = 0; c < 2; ++c) {
          bf16x8 bb = *(const bf16x8*)(psB + prd[c]);
          #pragma unroll
          for (int dt = 0; dt < 4; ++dt)
            accO[qs][dt] = __builtin_amdgcn_mfma_f32_16x16x32_bf16(vf[c][dt], bb, accO[qs][dt], 0, 0, 0);
          accL[qs] = __builtin_amdgcn_mfma_f32_16x16x32_bf16(ones, bb, accL[qs], 0, 0, 0);
        }
      }
    }

    fence_barrier();                          // all reads done -> buffer free
  }

  if (nch == 1) {
    #pragma unroll
    for (int qs = 0; qs < 2; ++qs) {
      const float rl = 1.0f / accL[qs][0];    // exact row sum, every lane
      const int qrow = q0w + qs * 16 + l15;
      #pragma unroll
      for (int dt = 0; dt < 4; ++dt) {
        ushort4 o;
        o.x = f2bf(accO[qs][dt][0] * rl);
        o.y = f2bf(accO[qs][dt][1] * rl);
        o.z = f2bf(accO[qs][dt][2] * rl);
        o.w = f2bf(accO[qs][dt][3] * rl);
        *(ushort4*)&Out[(size_t)qrow * 2048 + head * 64 + dt * 16 + lq * 4] = o;
      }
    }
    return;
  }

  // slot = head*36 + off(qt) + ch
  const int off = qt < 8 ? (qt - 4) * 2 : qt < 12 ? 8 + (qt - 8) * 3 : 20 + (qt - 12) * 4;
  const int slot = head * 36 + off + ch;
  u16* ob = Opart + (size_t)slot * 8192;
  #pragma unroll
  for (int qs = 0; qs < 2; ++qs) {
    const int row = w * 32 + qs * 16 + l15;
    #pragma unroll
    for (int dt = 0; dt < 4; ++dt) {
      ushort4 o;
      o.x = f2bf(accO[qs][dt][0]);
      o.y = f2bf(accO[qs][dt][1]);
      o.z = f2bf(accO[qs][dt][2]);
      o.w = f2bf(accO[qs][dt][3]);
      *(ushort4*)&ob[row * 64 + dt * 16 + lq * 4] = o;
    }
    if (lq == 0) Ml[(size_t)slot * 128 + row] = make_float2(m_[qs], accL[qs][0]);
  }
}

// ---------------- combine 2-4 partials -> attention output (bf16) ------------
__global__ __launch_bounds__(256) void attn_comb_k(const u16* __restrict__ Opart,
                                                   const float2* __restrict__ Ml,
                                                   u16* __restrict__ Out) {
  const int b = blockIdx.x;                 // ((head*12 + qt-4)*4 + rg)
  const int rg = b & 3;
  const int hq = b >> 2;
  const int head = hq / 12;
  const int qt = (hq - head * 12) + 4;
  const int nch = qt < 8 ? 2 : qt < 12 ? 3 : 4;
  const int off = qt < 8 ? (qt - 4) * 2 : qt < 12 ? 8 + (qt - 8) * 3 : 20 + (qt - 12) * 4;
  const int slot0 = head * 36 + off;
  const int rl = threadIdx.x >> 3;          // 0..31
  const int d8 = (threadIdx.x & 7) * 8;
  const int row = rg * 32 + rl;

  float gm = -1e30f;
  #pragma unroll 4
  for (int c = 0; c < nch; ++c)
    gm = fmaxf(gm, Ml[(size_t)(slot0 + c) * 128 + row].x);
  float den = 0.f;
  float num[8] = {};
  #pragma unroll 4
  for (int c = 0; c < nch; ++c) {
    float2 ml = Ml[(size_t)(slot0 + c) * 128 + row];
    float a = exp2f(ml.x - gm);
    den += a * ml.y;
    const u16* p = &Opart[(size_t)(slot0 + c) * 8192 + row * 64 + d8];
    ushort4 p0 = *(const ushort4*)p;
    ushort4 p1 = *(const ushort4*)(p + 4);
    num[0] += a * bf2f(p0.x); num[1] += a * bf2f(p0.y);
    num[2] += a * bf2f(p0.z); num[3] += a * bf2f(p0.w);
    num[4] += a * bf2f(p1.x); num[5] += a * bf2f(p1.y);
    num[6] += a * bf2f(p1.z); num[7] += a * bf2f(p1.w);
  }
  const float rd = 1.0f / den;
  ushort4 o0, o1;
  o0.x = f2bf(num[0] * rd); o0.y = f2bf(num[1] * rd);
  o0.z = f2bf(num[2] * rd); o0.w = f2bf(num[3] * rd);
  o1.x = f2bf(num[4] * rd); o1.y = f2bf(num[5] * rd);
  o1.z = f2bf(num[6] * rd); o1.w = f2bf(num[7] * rd);
  u16* op = &Out[(size_t)(qt * 128 + row) * 2048 + head * 64 + d8];
  *(ushort4*)op = o0;
  *(ushort4*)(op + 4) = o1;
}

extern "C" void kernel_launch(void* const* d_in, const int* in_sizes, int n_in,
                              void* d_out, int out_size, void* d_ws, size_t ws_size,
                              hipStream_t stream) {
  const float* x    = (const float*)d_in[0];
  const float* freq = (const float*)d_in[1];
  // d_in[2] = mask (known causal tril; not read)
  const float* wq   = (const float*)d_in[3];
  const float* wk   = (const float*)d_in[4];
  const float* wv   = (const float*)d_in[5];
  const float* wo   = (const float*)d_in[6];
  float* out = (float*)d_out;

  u16* x_bf   = (u16*)d_ws;                       // 2048*2048  (reused as Vt later)
  u16* wqkv_t = x_bf + (size_t)2048 * 2048;       // [3072][2048]
  u16* wo_t   = wqkv_t + (size_t)3072 * 2048;     // [2048][2048]
  u16* y      = wo_t + (size_t)2048 * 2048;       // [2048][3072] = Q | K | V
  u16* attn   = y + (size_t)2048 * 3072;          // [2048][2048]
  u16* vt     = x_bf;                             // [512][2048]
  u16* opart  = attn + (size_t)2048 * 2048;       // [1152][128][64] bf16 partials
  float2* ml  = (float2*)(opart + (size_t)1152 * 8192);   // [1152][128] (m,l)

  prep_k<<<14336, 256, 0, stream>>>(x, wq, wk, wv, wo, x_bf, wqkv_t, wo_t);
  gemm64_k<u16, 128, 24><<<768, 256, 0, stream>>>(x_bf, wqkv_t, y, 2048, 3072, 2048);
  ropevt_k<<<10496, 256, 0, stream>>>(y, freq, vt);
  attn_part_k<<<1280, 256, 0, stream>>>(y, vt, opart, ml, attn);
  attn_comb_k<<<1536, 256, 0, stream>>>(opart, ml, attn);
  gemm64_k<float, 128, 16><<<512, 256, 0, stream>>>(attn, wo_t, out, 2048, 2048, 2048);
}

// Round 24
// 133.293 us; speedup vs baseline: 1.0064x; 1.0064x over previous
//
#include <hip/hip_runtime.h>

typedef unsigned short u16;
typedef unsigned int u32;
typedef unsigned long long u64;

using bf16x8 = __bf16 __attribute__((ext_vector_type(8)));
using f32x4  = float  __attribute__((ext_vector_type(4)));

#define LDS_SPACE __attribute__((address_space(3)))
#define GLB_SPACE __attribute__((address_space(1)))

static __device__ __forceinline__ u16 f2bf(float f) {
  union { float f; u32 u; } c; c.f = f;
  u32 u = c.u;
  return (u16)((u + 0x7fffu + ((u >> 16) & 1u)) >> 16);   // RNE
}
static __device__ __forceinline__ float bf2f(u16 u) {
  union { u32 u; float f; } c; c.u = ((u32)u) << 16;
  return c.f;
}
static __device__ __forceinline__ float fmax3(float a, float b, float c) {
  return fmaxf(fmaxf(a, b), c);               // clang fuses to v_max3_f32
}

static __device__ __forceinline__ void fence_barrier() {
  asm volatile("" ::: "memory");
  __builtin_amdgcn_s_barrier();
  asm volatile("" ::: "memory");
}

constexpr float SC = 0.18033688011112042f;    // log2(e)/8 (folded into wq)

// items per head, sorted by descending chunk length (qt*4 + ch)
__device__ __constant__ unsigned char kItems[40] = {
  // len 8
  12, 28, 29, 42, 44, 45, 46, 57, 59, 60, 61, 62, 63,
  // len 7
  24, 25, 37, 38, 40, 41, 49, 51, 52, 53, 54, 55, 56, 58,
  // len 6
  8, 20, 21, 32, 33, 34, 36, 48, 50,
  // len 5
  16, 17,
  // len 4
  4,
  // len 2
  0
};

// ---------------- fused prep: x->bf16 convert + 4 weight transposes ----------
__global__ __launch_bounds__(256) void prep_k(const float* __restrict__ x,
                                              const float* __restrict__ wq,
                                              const float* __restrict__ wk,
                                              const float* __restrict__ wv,
                                              const float* __restrict__ wo,
                                              u16* __restrict__ x_bf,
                                              u16* __restrict__ wqkv_t,
                                              u16* __restrict__ wo_t) {
  const int b = blockIdx.x;
  if (b < 4096) {
    int i = b * 256 + threadIdx.x;
    float4 v = ((const float4*)x)[i];
    ushort4 o;
    o.x = f2bf(v.x); o.y = f2bf(v.y); o.z = f2bf(v.z); o.w = f2bf(v.w);
    ((ushort4*)x_bf)[i] = o;
    return;
  }
  const float* src; u16* dst; int C, bx, by; float scale = 1.0f;
  if (b < 8192)      { src = wq; dst = wqkv_t; C = 2048; int t = b - 4096; bx = t & 63; by = t >> 6; scale = SC; }
  else if (b < 9216) { src = wk; dst = wqkv_t + (size_t)2048 * 2048; C = 512; int t = b - 8192; bx = t & 15; by = t >> 4; }
  else if (b < 10240){ src = wv; dst = wqkv_t + (size_t)2560 * 2048; C = 512; int t = b - 9216; bx = t & 15; by = t >> 4; }
  else               { src = wo; dst = wo_t; C = 2048; int t = b - 10240; bx = t & 63; by = t >> 6; }
  __shared__ float t[32][33];
  const int lx = threadIdx.x & 31, ly = threadIdx.x >> 5;
  const int r0 = by * 32, c0 = bx * 32;
  #pragma unroll
  for (int i = 0; i < 32; i += 8)
    t[ly + i][lx] = src[(size_t)(r0 + ly + i) * C + c0 + lx];
  __syncthreads();
  #pragma unroll
  for (int i = 0; i < 32; i += 8)
    dst[(size_t)(c0 + ly + i) * 2048 + r0 + lx] = f2bf(t[lx][ly + i] * scale);
}

// ---------------- merged RoPE (Q|K cols) + V transpose (disjoint cols) -------
__global__ __launch_bounds__(256) void ropevt_k(u16* __restrict__ Y,
                                                const float* __restrict__ freq,
                                                u16* __restrict__ Vt) {
  const int b = blockIdx.x;
  if (b < 10240) {
    int idx = b * 256 + threadIdx.x;
    int s = idx / 1280;
    int rem = idx - s * 1280;
    int h = rem >> 5;
    int i = rem & 31;
    int col = (h < 32) ? (h * 64 + 2 * i) : (2048 + (h - 32) * 64 + 2 * i);
    float ang = freq[s * 32 + i];
    float sn, cs;
    sincosf(ang, &sn, &cs);
    size_t base = (size_t)s * 3072 + col;
    float e = bf2f(Y[base]), o = bf2f(Y[base + 1]);
    Y[base]     = f2bf(e * cs - o * sn);
    Y[base + 1] = f2bf(e * sn + o * cs);
    return;
  }
  __shared__ u16 t[64][72];
  const int tb = b - 10240;                  // 0..255
  const int s0 = (tb & 31) * 64;
  const int c0 = (tb >> 5) * 64;
  const int lx = threadIdx.x & 63, ly = threadIdx.x >> 6;
  #pragma unroll
  for (int i = 0; i < 64; i += 4)
    t[i + ly][lx] = Y[(size_t)(s0 + i + ly) * 3072 + 2560 + c0 + lx];
  __syncthreads();
  #pragma unroll
  for (int i = 0; i < 64; i += 4)
    Vt[(size_t)(c0 + i + ly) * 2048 + s0 + lx] = t[lx][i + ly];
}

// ------- GEMM: C[M][N]=A[M][K]*Bt[N][K]^T, BM=64, BN templated, BK=64 -------
// 1D grid + bijective XCD swizzle (nwg % 8 == 0): chunk per XCD -> L2 locality.
template <typename OutT, int BN, int GX>
__global__ __launch_bounds__(256) void gemm64_k(const u16* __restrict__ A,
                                                const u16* __restrict__ Bt,
                                                OutT* __restrict__ C,
                                                int M, int N, int K) {
  constexpr int WN = BN / 32;
  __shared__ u16 As[2][64 * 64];
  __shared__ u16 Bs[2][BN * 64];
  const int tid = threadIdx.x, lane = tid & 63, w = tid >> 6;
  const int wr = w >> 1, wc = w & 1;
  const int nwg = gridDim.x;
  const int bsw = (blockIdx.x & 7) * (nwg >> 3) + ((int)blockIdx.x >> 3);
  const int bm = bsw / GX, bn = bsw - bm * GX;
  const int l15 = lane & 15, lq = lane >> 4;
  f32x4 acc[2][WN] = {};

  const int srow8 = lane >> 3;
  const int scolb = ((lane & 7) ^ srow8) * 16;
  const u16* AgR = A + (size_t)(bm * 64 + w * 16 + srow8) * K;
  const u16* BgR = Bt + (size_t)(bn * BN + w * (BN / 4) + srow8) * K;

  auto stage = [&](int buf, int k0) {
    #pragma unroll
    for (int i = 0; i < 2; ++i)
      __builtin_amdgcn_global_load_lds(
          (const GLB_SPACE u32*)((const char*)(AgR + (size_t)i * 8 * K + k0) + scolb),
          (LDS_SPACE u32*)&As[buf][(w * 16 + i * 8) * 64], 16, 0, 0);
    #pragma unroll
    for (int i = 0; i < WN; ++i)
      __builtin_amdgcn_global_load_lds(
          (const GLB_SPACE u32*)((const char*)(BgR + (size_t)i * 8 * K + k0) + scolb),
          (LDS_SPACE u32*)&Bs[buf][(w * (BN / 4) + i * 8) * 64], 16, 0, 0);
  };

  stage(0, 0);
  asm volatile("s_waitcnt vmcnt(0)" ::: "memory");
  fence_barrier();

  for (int k0 = 0; k0 < K; k0 += 64) {
    const int p = (k0 >> 6) & 1;
    if (k0 + 64 < K) stage(p ^ 1, k0 + 64);

    #pragma unroll
    for (int kk = 0; kk < 2; ++kk) {
      bf16x8 a[2], b[WN];
      #pragma unroll
      for (int m = 0; m < 2; ++m) {
        const int ra = wr * 32 + m * 16 + l15;
        a[m] = *(const bf16x8*)&As[p][ra * 64 + (((kk * 4 + lq) ^ (ra & 7)) << 3)];
      }
      #pragma unroll
      for (int n = 0; n < WN; ++n) {
        const int rb = wc * (BN / 2) + n * 16 + l15;
        b[n] = *(const bf16x8*)&Bs[p][rb * 64 + (((kk * 4 + lq) ^ (rb & 7)) << 3)];
      }
      #pragma unroll
      for (int m = 0; m < 2; ++m)
        #pragma unroll
        for (int n = 0; n < WN; ++n)
          acc[m][n] = __builtin_amdgcn_mfma_f32_16x16x32_bf16(a[m], b[n], acc[m][n], 0, 0, 0);
    }

    asm volatile("s_waitcnt vmcnt(0)" ::: "memory");
    fence_barrier();
  }

  const int r0 = bm * 64 + wr * 32 + lq * 4;
  const int c0 = bn * BN + wc * (BN / 2) + l15;
  #pragma unroll
  for (int m = 0; m < 2; ++m)
    #pragma unroll
    for (int n = 0; n < WN; ++n)
      #pragma unroll
      for (int r = 0; r < 4; ++r) {
        float v = acc[m][n][r];
        size_t off = (size_t)(r0 + m * 16 + r) * N + (c0 + n * 16);
        if constexpr (sizeof(OutT) == 2) ((u16*)C)[off] = f2bf(v);
        else C[off] = v;
      }
}

// ---------------- Split-K flash attention: single-buffer K/V -----------------
// l via ones-A MFMA; max via v_max3. Stable best config (~51us).
__global__ __launch_bounds__(256, 3) void attn_part_k(const u16* __restrict__ Y,
                                                      const u16* __restrict__ Vtg,
                                                      u16* __restrict__ Opart,
                                                      float2* __restrict__ Ml,
                                                      u16* __restrict__ Out) {
  __shared__ u16 Ks[64 * 64];
  __shared__ u16 Vs[64 * 64];
  __shared__ u32 Ps[4][16 * 32];
  const int w = threadIdx.x >> 6, lane = threadIdx.x & 63;
  const int l15 = lane & 15, lq = lane >> 4;

  const int b = (int)blockIdx.x;
  const int head = b & 31;
  const int idx = b >> 5;                      // 0..39, descending chunk length
  const int v = kItems[idx];
  const int qt = v >> 2, ch = v & 3;
  const int kvh = head >> 2;
  const int ntiles = 2 * qt + 2;
  const int nch = qt < 4 ? 1 : qt < 8 ? 2 : qt < 12 ? 3 : 4;
  const int tstart = (ch * ntiles) / nch;
  const int tend = ((ch + 1) * ntiles) / nch;
  const int q0w = qt * 128 + w * 32;

  const int srow = lane >> 3;
  const int scolb = ((lane & 7) ^ srow) * 16;
  const char* gkB = (const char*)(Y + (size_t)(w * 16 + srow) * 3072 + 2048 + kvh * 64) + scolb;
  const char* gvB = (const char*)(Vtg + (size_t)(kvh * 64 + w * 16 + srow) * 2048) + scolb;

  auto stage = [&](int t) {
    const size_t t0 = (size_t)t * 64;
    #pragma unroll
    for (int i = 0; i < 2; ++i) {
      __builtin_amdgcn_global_load_lds((const GLB_SPACE u32*)(gkB + t0 * 6144 + (size_t)i * 49152),
                                       (LDS_SPACE u32*)&Ks[(w * 16 + i * 8) * 64], 16, 0, 0);
      __builtin_amdgcn_global_load_lds((const GLB_SPACE u32*)(gvB + t0 * 2 + (size_t)i * 32768),
                                       (LDS_SPACE u32*)&Vs[(w * 16 + i * 8) * 64], 16, 0, 0);
    }
  };

  // hoisted LDS byte offsets
  int rowB[4], xk[2], pwr[4], prd[2];
  #pragma unroll
  for (int kt = 0; kt < 4; ++kt) rowB[kt] = (kt * 16 + l15) * 128;
  #pragma unroll
  for (int kk = 0; kk < 2; ++kk) xk[kk] = (((kk * 4 + lq) ^ (l15 & 7)) << 4);
  #pragma unroll
  for (int n = 0; n < 4; ++n)
    pwr[n] = (l15 * 32 + ((lq * 2 + n * 8) ^ ((l15 & 7) << 2))) * 4;
  #pragma unroll
  for (int c = 0; c < 2; ++c)
    prd[c] = l15 * 128 + (((c * 32 + lq * 8) ^ ((l15 & 7) << 3)) << 1);

  bf16x8 ones;
  {
    union { u16 u; __bf16 h; } cv; cv.u = 0x3F80;   // bf16 1.0
    #pragma unroll
    for (int i = 0; i < 8; ++i) ones[i] = cv.h;
  }

  bf16x8 qf[2][2];
  #pragma unroll
  for (int qs = 0; qs < 2; ++qs)
    #pragma unroll
    for (int kk = 0; kk < 2; ++kk)
      qf[qs][kk] = *(const bf16x8*)&Y[(size_t)(q0w + qs * 16 + l15) * 3072 +
                                      head * 64 + kk * 32 + lq * 8];

  float m_[2] = { -1e30f, -1e30f };
  f32x4 accL[2] = {};                          // row sums via ones-MFMA
  f32x4 accO[2][4] = {};

  for (int t = tstart; t < tend; ++t) {
    stage(t);
    asm volatile("s_waitcnt vmcnt(0)" ::: "memory");
    fence_barrier();                          // buffer ready

    const int t0 = t * 64;
    if (t0 <= q0w + 31) {
      const char* KbC = (const char*)Ks;
      const char* VbC = (const char*)Vs;

      f32x4 sc[2][4] = {};
      #pragma unroll
      for (int kk = 0; kk < 2; ++kk)
        #pragma unroll
        for (int kt = 0; kt < 4; ++kt) {
          bf16x8 a = *(const bf16x8*)(KbC + rowB[kt] + xk[kk]);
          sc[0][kt] = __builtin_amdgcn_mfma_f32_16x16x32_bf16(a, qf[0][kk], sc[0][kt], 0, 0, 0);
          sc[1][kt] = __builtin_amdgcn_mfma_f32_16x16x32_bf16(a, qf[1][kk], sc[1][kt], 0, 0, 0);
        }

      bf16x8 vf[2][4];
      #pragma unroll
      for (int c = 0; c < 2; ++c)
        #pragma unroll
        for (int dt = 0; dt < 4; ++dt)
          vf[c][dt] = *(const bf16x8*)(VbC + rowB[dt] + xk[c]);

      #pragma unroll
      for (int qs = 0; qs < 2; ++qs) {
        const int qsmin = q0w + qs * 16;
        if (t0 > qsmin + 15) continue;
        const int qrow = qsmin + l15;
        if (t0 + 63 > qsmin) {
          #pragma unroll
          for (int n = 0; n < 4; ++n)
            #pragma unroll
            for (int rr = 0; rr < 4; ++rr)
              if (t0 + n * 16 + lq * 4 + rr > qrow) sc[qs][n][rr] = -1e30f;
        }
        // v_max3 tree (8 ops over 16 values)
        float mx = fmaxf(
            fmax3(fmax3(sc[qs][0][0], sc[qs][0][1], sc[qs][0][2]),
                  fmax3(sc[qs][0][3], sc[qs][1][0], sc[qs][1][1]),
                  fmax3(sc[qs][1][2], sc[qs][1][3], sc[qs][2][0])),
            fmax3(fmax3(sc[qs][2][1], sc[qs][2][2], sc[qs][2][3]),
                  fmax3(sc[qs][3][0], sc[qs][3][1], sc[qs][3][2]),
                  sc[qs][3][3]));

        if (__any(mx > m_[qs] + 7.25f)) {      // rare rescale (defer-max)
          float mf = mx;
          mf = fmaxf(mf, __shfl_xor(mf, 16));
          mf = fmaxf(mf, __shfl_xor(mf, 32));
          const float mnew = fmaxf(m_[qs], mf);
          const float alpha = exp2f(m_[qs] - mnew);
          accL[qs] *= alpha;
          #pragma unroll
          for (int dt = 0; dt < 4; ++dt) accO[qs][dt] *= alpha;
          m_[qs] = mnew;
        }
        const float mS = m_[qs];
        char* psB = (char*)Ps[w];
        #pragma unroll
        for (int n = 0; n < 4; ++n) {
          float p0 = exp2f(sc[qs][n][0] - mS);
          float p1 = exp2f(sc[qs][n][1] - mS);
          float p2 = exp2f(sc[qs][n][2] - mS);
          float p3 = exp2f(sc[qs][n][3] - mS);
          u32 w0, w1;
          asm("v_cvt_pk_bf16_f32 %0, %1, %2" : "=v"(w0) : "v"(p0), "v"(p1));
          asm("v_cvt_pk_bf16_f32 %0, %1, %2" : "=v"(w1) : "v"(p2), "v"(p3));
          *(u64*)(psB + pwr[n]) = (u64)w0 | ((u64)w1 << 32);
        }

        #pragma unroll
        for (int c = 0; c < 2; ++c) {
          bf16x8 bb = *(const bf16x8*)(psB + prd[c]);
          #pragma unroll
          for (int dt = 0; dt < 4; ++dt)
            accO[qs][dt] = __builtin_amdgcn_mfma_f32_16x16x32_bf16(vf[c][dt], bb, accO[qs][dt], 0, 0, 0);
          accL[qs] = __builtin_amdgcn_mfma_f32_16x16x32_bf16(ones, bb, accL[qs], 0, 0, 0);
        }
      }
    }

    fence_barrier();                          // all reads done -> buffer free
  }

  if (nch == 1) {
    #pragma unroll
    for (int qs = 0; qs < 2; ++qs) {
      const float rl = 1.0f / accL[qs][0];    // exact row sum, every lane
      const int qrow = q0w + qs * 16 + l15;
      #pragma unroll
      for (int dt = 0; dt < 4; ++dt) {
        ushort4 o;
        o.x = f2bf(accO[qs][dt][0] * rl);
        o.y = f2bf(accO[qs][dt][1] * rl);
        o.z = f2bf(accO[qs][dt][2] * rl);
        o.w = f2bf(accO[qs][dt][3] * rl);
        *(ushort4*)&Out[(size_t)qrow * 2048 + head * 64 + dt * 16 + lq * 4] = o;
      }
    }
    return;
  }

  // slot = head*36 + off(qt) + ch
  const int off = qt < 8 ? (qt - 4) * 2 : qt < 12 ? 8 + (qt - 8) * 3 : 20 + (qt - 12) * 4;
  const int slot = head * 36 + off + ch;
  u16* ob = Opart + (size_t)slot * 8192;
  #pragma unroll
  for (int qs = 0; qs < 2; ++qs) {
    const int row = w * 32 + qs * 16 + l15;
    #pragma unroll
    for (int dt = 0; dt < 4; ++dt) {
      ushort4 o;
      o.x = f2bf(accO[qs][dt][0]);
      o.y = f2bf(accO[qs][dt][1]);
      o.z = f2bf(accO[qs][dt][2]);
      o.w = f2bf(accO[qs][dt][3]);
      *(ushort4*)&ob[row * 64 + dt * 16 + lq * 4] = o;
    }
    if (lq == 0) Ml[(size_t)slot * 128 + row] = make_float2(m_[qs], accL[qs][0]);
  }
}

// ---------------- combine 2-4 partials -> attention output (bf16) ------------
__global__ __launch_bounds__(256) void attn_comb_k(const u16* __restrict__ Opart,
                                                   const float2* __restrict__ Ml,
                                                   u16* __restrict__ Out) {
  const int b = blockIdx.x;                 // ((head*12 + qt-4)*4 + rg)
  const int rg = b & 3;
  const int hq = b >> 2;
  const int head = hq / 12;
  const int qt = (hq - head * 12) + 4;
  const int nch = qt < 8 ? 2 : qt < 12 ? 3 : 4;
  const int off = qt < 8 ? (qt - 4) * 2 : qt < 12 ? 8 + (qt - 8) * 3 : 20 + (qt - 12) * 4;
  const int slot0 = head * 36 + off;
  const int rl = threadIdx.x >> 3;          // 0..31
  const int d8 = (threadIdx.x & 7) * 8;
  const int row = rg * 32 + rl;

  float gm = -1e30f;
  #pragma unroll 4
  for (int c = 0; c < nch; ++c)
    gm = fmaxf(gm, Ml[(size_t)(slot0 + c) * 128 + row].x);
  float den = 0.f;
  float num[8] = {};
  #pragma unroll 4
  for (int c = 0; c < nch; ++c) {
    float2 ml = Ml[(size_t)(slot0 + c) * 128 + row];
    float a = exp2f(ml.x - gm);
    den += a * ml.y;
    const u16* p = &Opart[(size_t)(slot0 + c) * 8192 + row * 64 + d8];
    ushort4 p0 = *(const ushort4*)p;
    ushort4 p1 = *(const ushort4*)(p + 4);
    num[0] += a * bf2f(p0.x); num[1] += a * bf2f(p0.y);
    num[2] += a * bf2f(p0.z); num[3] += a * bf2f(p0.w);
    num[4] += a * bf2f(p1.x); num[5] += a * bf2f(p1.y);
    num[6] += a * bf2f(p1.z); num[7] += a * bf2f(p1.w);
  }
  const float rd = 1.0f / den;
  ushort4 o0, o1;
  o0.x = f2bf(num[0] * rd); o0.y = f2bf(num[1] * rd);
  o0.z = f2bf(num[2] * rd); o0.w = f2bf(num[3] * rd);
  o1.x = f2bf(num[4] * rd); o1.y = f2bf(num[5] * rd);
  o1.z = f2bf(num[6] * rd); o1.w = f2bf(num[7] * rd);
  u16* op = &Out[(size_t)(qt * 128 + row) * 2048 + head * 64 + d8];
  *(ushort4*)op = o0;
  *(ushort4*)(op + 4) = o1;
}

extern "C" void kernel_launch(void* const* d_in, const int* in_sizes, int n_in,
                              void* d_out, int out_size, void* d_ws, size_t ws_size,
                              hipStream_t stream) {
  const float* x    = (const float*)d_in[0];
  const float* freq = (const float*)d_in[1];
  // d_in[2] = mask (known causal tril; not read)
  const float* wq   = (const float*)d_in[3];
  const float* wk   = (const float*)d_in[4];
  const float* wv   = (const float*)d_in[5];
  const float* wo   = (const float*)d_in[6];
  float* out = (float*)d_out;

  u16* x_bf   = (u16*)d_ws;                       // 2048*2048  (reused as Vt later)
  u16* wqkv_t = x_bf + (size_t)2048 * 2048;       // [3072][2048]
  u16* wo_t   = wqkv_t + (size_t)3072 * 2048;     // [2048][2048]
  u16* y      = wo_t + (size_t)2048 * 2048;       // [2048][3072] = Q | K | V
  u16* attn   = y + (size_t)2048 * 3072;          // [2048][2048]
  u16* vt     = x_bf;                             // [512][2048]
  u16* opart  = attn + (size_t)2048 * 2048;       // [1152][128][64] bf16 partials
  float2* ml  = (float2*)(opart + (size_t)1152 * 8192);   // [1152][128] (m,l)

  prep_k<<<14336, 256, 0, stream>>>(x, wq, wk, wv, wo, x_bf, wqkv_t, wo_t);
  gemm64_k<u16, 128, 24><<<768, 256, 0, stream>>>(x_bf, wqkv_t, y, 2048, 3072, 2048);
  ropevt_k<<<10496, 256, 0, stream>>>(y, freq, vt);
  attn_part_k<<<1280, 256, 0, stream>>>(y, vt, opart, ml, attn);
  attn_comb_k<<<1536, 256, 0, stream>>>(opart, ml, attn);
  gemm64_k<float, 64, 32><<<1024, 256, 0, stream>>>(attn, wo_t, out, 2048, 2048, 2048);
}